// Round 12
// baseline (1797.397 us; speedup 1.0000x reference)
//
#include <hip/hip_runtime.h>
#include <hip/hip_bf16.h>
#include <hip/hip_fp16.h>
#include <float.h>
#include <math.h>

#define DEVFN __device__ __forceinline__

// Compiler-only fence: wave64 executes DS ops in order; stops reordering.
DEVFN void wavefence() { __builtin_amdgcn_wave_barrier(); }

namespace {
constexpr int Bq = 4, Nq = 8192, Cq = 32, Kq = 16;
constexpr int PTS = Bq * Nq;          // 32768 points
constexpr int CH = 8;                  // knn candidate chunks
constexpr int CAND = Nq / CH;          // 1024 candidates per chunk
constexpr double ROWS = 524288.0;      // PTS * Kq

// dstat/bnp region bases (each region: [sum|mean x128][sumsq|scale x128])
constexpr int DS_Y = 0, DS_Z = 256, DS_G = 512, DS_H1 = 768, DS_H2 = 1024;

// workspace byte offsets
constexpr size_t OFF_A    = 0;                         // knn_d (16MB) -> reused as g_raw
constexpr size_t OFF_B    = (size_t)16 << 20;          // knn_j (16MB) -> reused as agg
constexpr size_t OFF_IDX  = (size_t)32 << 20;          // idx (2MB)
constexpr size_t OFF_DST  = (size_t)34 << 20;          // dstat (1280 doubles)
constexpr size_t OFF_MST  = ((size_t)34 << 20) + 10240; // mstat (36*37 floats)
constexpr size_t OFF_BNP  = ((size_t)34 << 20) + 16384; // bnp (1280 floats)
constexpr size_t OFF_H1   = ((size_t)34 << 20) + 32768; // h1 raw (16MB)
constexpr size_t OFF_H2   = ((size_t)50 << 20) + 32768; // h2 raw (16MB)
}

// ---------------- KNN: two-phase select-then-collect ------------------------
#define TOP16_DECL                                                           \
  float e0=FLT_MAX,e1=FLT_MAX,e2=FLT_MAX,e3=FLT_MAX,e4=FLT_MAX,e5=FLT_MAX,  \
        e6=FLT_MAX,e7=FLT_MAX,e8=FLT_MAX,e9=FLT_MAX,e10=FLT_MAX,            \
        e11=FLT_MAX,e12=FLT_MAX,e13=FLT_MAX,e14=FLT_MAX,e15=FLT_MAX;

// Pair-merge: merge sorted e0..e15 with sorted pair (b0<=b1), keep 16 smallest.
// R[i] = min3(e_i, max(e_{i-1},b0), max(e_{i-2},b1)); evaluate top-down so each
// line reads only old (lower-index) values. min3/max fuse to v_min3/v_max.
#define PMERGE(i, im1, im2)                                                  \
  e##i = fminf(fminf(e##i, fmaxf(e##im1, b0)), fmaxf(e##im2, b1));
#define PMERGE_ALL                                                           \
  PMERGE(15,14,13) PMERGE(14,13,12) PMERGE(13,12,11) PMERGE(12,11,10)        \
  PMERGE(11,10,9) PMERGE(10,9,8) PMERGE(9,8,7) PMERGE(8,7,6) PMERGE(7,6,5)   \
  PMERGE(6,5,4) PMERGE(5,4,3) PMERGE(4,3,2) PMERGE(3,2,1) PMERGE(2,1,0)      \
  e1 = fminf(fminf(e1, fmaxf(e0, b0)), b1);                                  \
  e0 = fminf(e0, b0);

DEVFN float distf(const float4 c, const float qx, const float qy, const float qz) {
  const float dx = qx - c.x, dy = qy - c.y, dz = qz - c.z;
  return __fadd_rn(__fadd_rn(__fmul_rn(dx, dx), __fmul_rn(dy, dy)), __fmul_rn(dz, dz));
}

__global__ __launch_bounds__(256, 4) void knn_chunk_kernel(const float* __restrict__ xyz,
                                                           float* __restrict__ pd,
                                                           int* __restrict__ pj) {
  const int b = blockIdx.z;
  const int ch = blockIdx.y;
  const int n = blockIdx.x * 256 + threadIdx.x;
  __shared__ __align__(16) float4 tile[CAND];
  const float* xb = xyz + (size_t)b * Nq * 3;
  for (int t = threadIdx.x; t < CAND; t += 256) {
    const int j = ch * CAND + t;
    tile[t] = make_float4(xb[j * 3], xb[j * 3 + 1], xb[j * 3 + 2], 0.f);
  }
  __syncthreads();
  const float qx = xb[n * 3], qy = xb[n * 3 + 1], qz = xb[n * 3 + 2];
  // scan 1: 16 smallest distance VALUES via pair-merge network (values only)
  TOP16_DECL;
  for (int t = 0; t < CAND; t += 2) {
    const float u0 = distf(tile[t], qx, qy, qz);
    const float u1 = distf(tile[t + 1], qx, qy, qz);
    const float b0 = fminf(u0, u1), b1 = fmaxf(u0, u1);
    PMERGE_ALL
  }
  const float kth = e15;
  // scan 2: collect indices d < kth (ascending order == stable top_k) and
  // fold the tie search in: record first index with d == kth branch-free.
  const size_t base = (((size_t)b * Nq + n) * CH + ch) * Kq;
  int cnt = 0, tfirst = -1;
  for (int t = 0; t < CAND; ++t) {
    const float d = distf(tile[t], qx, qy, qz);
    if (d < kth) { pd[base + cnt] = d; pj[base + cnt] = ch * CAND + t; ++cnt; }
    tfirst = (d == kth && tfirst < 0) ? t : tfirst;
  }
  if (cnt == 15) {  // typical (all-distinct): exactly one kth tie -> done
    pd[base + 15] = kth; pj[base + 15] = ch * CAND + tfirst; cnt = 16;
  }
  if (__any(cnt < 16)) {  // rare multi-tie fallback (exactness)
    for (int t = 0; t < CAND; ++t) {
      const float d = distf(tile[t], qx, qy, qz);
      if (d == kth && cnt < 16) { pd[base + cnt] = d; pj[base + cnt] = ch * CAND + t; ++cnt; }
    }
  }
}

__global__ __launch_bounds__(256, 4) void knn_merge_kernel(const float* __restrict__ pd,
                                                           const int* __restrict__ pj,
                                                           int* __restrict__ idxo) {
  const int q = blockIdx.x * 256 + threadIdx.x;
  const float* dp = pd + (size_t)q * CH * Kq;
  const int* jp = pj + (size_t)q * CH * Kq;
  TOP16_DECL;
  for (int t = 0; t < CH * Kq; t += 4) {
    const float4 v = *(const float4*)(dp + t);
    { const float b0 = fminf(v.x, v.y), b1 = fmaxf(v.x, v.y); PMERGE_ALL }
    { const float b0 = fminf(v.z, v.w), b1 = fmaxf(v.z, v.w); PMERGE_ALL }
  }
  const float kth = e15;
  int* op = idxo + (size_t)q * Kq;
  int cnt = 0;
  for (int t = 0; t < CH * Kq; ++t) {
    const float d = dp[t];
    if (d < kth) { op[cnt] = jp[t]; ++cnt; }
  }
  for (int t = 0; t < CH * Kq; ++t) {
    const float d = dp[t];
    if (d == kth && cnt < 16) { op[cnt] = jp[t]; ++cnt; }
  }
}

// ---------------- gather pipeline pieces ------------------------------------
struct PF { float4 f0, f1; float nx, ny, nz; };

DEVFN PF issue_feat(const float* __restrict__ features, const float* __restrict__ xyz,
                    int p, int j, int sub) {
  const int b = p >> 13;
  const float* fr = features + ((size_t)b * Nq + j) * Cq;
  const float* xb = xyz + ((size_t)b * Nq + j) * 3;
  PF r;
  r.f0 = *(const float4*)(fr + sub * 8);
  r.f1 = *(const float4*)(fr + sub * 8 + 4);
  r.nx = xb[0]; r.ny = xb[1]; r.nz = xb[2];
  return r;
}

DEVFN int issue_idx(const int* __restrict__ idx, int p, int lane) {
  return idx[(size_t)p * Kq + (lane >> 2)];
}

DEVFN float3 issue_query(const float* __restrict__ xyz, int p) {
  const float* q = xyz + (size_t)p * 3;  // [B,N,3] flat: p = b*Nq+n
  return make_float3(q[0], q[1], q[2]);
}

// enc row layout: [rel.x rel.y rel.z dist f0..f31] padded to 40 floats.
DEVFN void commit_enc(float* __restrict__ enc, int lane, const PF& pf,
                      float qx, float qy, float qz) {
  const int k = lane >> 2, sub = lane & 3;
  float* er = enc + k * 40;
  *(float4*)(er + 4 + sub * 8) = pf.f0;
  *(float4*)(er + 4 + sub * 8 + 4) = pf.f1;
  if (sub == 0) {
    const float rx = pf.nx - qx, ry = pf.ny - qy, rz = pf.nz - qz;
    const float ss = rx * rx + ry * ry + rz * rz;
    *(float4*)er = make_float4(rx, ry, rz, sqrtf(fmaxf(ss, 1e-12f)));
  }
}

// dot(enc_row[0..35], f16-packed weights) -- 4 accumulators; float(half)*float
// pattern fuses to v_fma_mix (18 VGPRs vs 36 for fp32 weights).
DEVFN float dot36h(const float* __restrict__ er, const __half2* __restrict__ wh) {
  float a0 = 0.f, a1 = 0.f, a2 = 0.f, a3 = 0.f;
#pragma unroll
  for (int c4 = 0; c4 < 9; ++c4) {
    const float4 ev = *(const float4*)(er + c4 * 4);
    const __half2 w0 = wh[c4 * 2], w1 = wh[c4 * 2 + 1];
    a0 += ev.x * __low2float(w0);
    a1 += ev.y * __high2float(w0);
    a2 += ev.z * __low2float(w1);
    a3 += ev.w * __high2float(w1);
  }
  return (a0 + a1) + (a2 + a3);
}

// dot(x_row[0..63], f16-packed weights) -- 32 VGPRs vs 64 for fp32.
DEVFN float dot64h(const float* __restrict__ xr, const __half2* __restrict__ sh) {
  float a0 = 0.f, a1 = 0.f, a2 = 0.f, a3 = 0.f;
#pragma unroll
  for (int c4 = 0; c4 < 16; ++c4) {
    const float4 xv = *(const float4*)(xr + c4 * 4);
    const __half2 s0 = sh[c4 * 2], s1 = sh[c4 * 2 + 1];
    a0 += xv.x * __low2float(s0);
    a1 += xv.y * __high2float(s0);
    a2 += xv.z * __low2float(s1);
    a3 += xv.w * __high2float(s1);
  }
  return (a0 + a1) + (a2 + a3);
}

// pipeline open/close macros (body sits between them as ordinary code).
#define GATHER_PROLOGUE                                                      \
  int p = wid;                                                               \
  int jc = issue_idx(idx, p, lane);                                          \
  PF cur = issue_feat(features, xyz, p, jc, lane & 3);                       \
  float3 qc = issue_query(xyz, p);                                           \
  int pn0 = p + nw; if (pn0 >= PTS) pn0 = p;                                 \
  int jn = issue_idx(idx, pn0, lane);                                        \
  float3 qn = issue_query(xyz, pn0);                                         \
  for (; p < PTS; p += nw) {                                                 \
    int pn = p + nw; if (pn >= PTS) pn = p;                                  \
    int pn2 = pn + nw; if (pn2 >= PTS) pn2 = pn;                             \
    PF nxt = issue_feat(features, xyz, pn, jn, lane & 3);                    \
    const int jn2 = issue_idx(idx, pn2, lane);                               \
    const float3 q2 = issue_query(xyz, pn2);                                 \
    commit_enc(enc, lane, cur, qc.x, qc.y, qc.z);                            \
    wavefence();

#define GATHER_EPILOGUE                                                      \
    wavefence();                                                             \
    cur = nxt; qc = qn; qn = q2; jn = jn2;                                   \
  }

// ---------------- encM: M = sum enc^T enc (36x36), v = sum enc --------------
__global__ __launch_bounds__(256) void encM_kernel(const float* __restrict__ xyz,
                                                   const float* __restrict__ features,
                                                   const int* __restrict__ idx,
                                                   float* __restrict__ mstat) {
  __shared__ __align__(16) float encS[4][16 * 40];
  __shared__ float mred[4][36 * 37];
  const int lane = threadIdx.x & 63, wv = threadIdx.x >> 6;
  float* enc = encS[wv];
  const int li = (lane < 36) ? lane : 0;  // clamp: lanes>=36 compute junk, never stored
  float macc[36];
#pragma unroll
  for (int i = 0; i < 36; ++i) macc[i] = 0.f;
  float vacc = 0.f;
  const int wid = blockIdx.x * 4 + wv, nw = gridDim.x * 4;
  GATHER_PROLOGUE
#pragma unroll
    for (int k = 0; k < 16; ++k) {
      const float* er = enc + k * 40;
      const float ei = er[li];
      vacc += ei;
#pragma unroll
      for (int c4 = 0; c4 < 9; ++c4) {
        const float4 ev = *(const float4*)(er + c4 * 4);
        macc[c4 * 4 + 0] += ei * ev.x;
        macc[c4 * 4 + 1] += ei * ev.y;
        macc[c4 * 4 + 2] += ei * ev.z;
        macc[c4 * 4 + 3] += ei * ev.w;
      }
    }
  GATHER_EPILOGUE
  if (lane < 36) {
#pragma unroll
    for (int j = 0; j < 36; ++j) mred[wv][lane * 37 + j] = macc[j];
    mred[wv][lane * 37 + 36] = vacc;
  }
  __syncthreads();
  for (int t = threadIdx.x; t < 36 * 37; t += 256) {
    const float s = mred[0][t] + mred[1][t] + mred[2][t] + mred[3][t];
    atomicAdd(&mstat[t], s);
  }
}

// y-stat finalize from moments (double precision). thread t = br*64+o.
__global__ void y_finalize_kernel(const float* __restrict__ mstat,
                                  const float* __restrict__ wl1,
                                  const float* __restrict__ wl2,
                                  float* __restrict__ bnp) {
  const int t = threadIdx.x;  // 128
  const int br = t >> 6, o = t & 63;
  const float* W = br ? wl2 : wl1;
  double wrow[36];
  for (int c = 0; c < 36; ++c) wrow[c] = (double)W[o * 36 + c];
  double mean = 0.0, ey2 = 0.0;
  for (int i = 0; i < 36; ++i) {
    mean += wrow[i] * (double)mstat[i * 37 + 36];
    double rowacc = 0.0;
    for (int j = 0; j < 36; ++j) rowacc += wrow[j] * (double)mstat[i * 37 + j];
    ey2 += wrow[i] * rowacc;
  }
  const double invR = 1.0 / ROWS;
  mean *= invR; ey2 *= invR;
  const double var = ey2 - mean * mean;
  bnp[DS_Y + br * 64 + o] = (float)mean;
  bnp[DS_Y + 128 + br * 64 + o] = (float)(1.0 / sqrt(var + 1e-5));
}

// ---------------- generic BN stat finalize: mean + rsqrt(var+eps) -----------
__global__ void bn_finalize_kernel(const double* __restrict__ dstat, float* __restrict__ bnp,
                                   int base, double invc) {
  const int t = threadIdx.x;  // 128 threads
  const double m = dstat[base + t] * invc;
  const double v = dstat[base + 128 + t] * invc - m * m;
  bnp[base + t] = (float)m;
  bnp[base + 128 + t] = (float)(1.0 / sqrt(v + 1e-5));
}

// ---------------- passA: x = relu(bn(y)); z = x @ sw1^T; z stats ------------
// PLAIN __launch_bounds__(256): rounds 8-11 proved any occupancy hint
// ((256,4) or waves_per_eu(4,4)) drives the allocator to a 64-VGPR target
// and ~1.2GB of scratch spill; plain bounds (round 7) let it size to the
// live state (no spill). f16 state ~116 VGPR also permits 4 blocks/CU.
__global__ __launch_bounds__(256)
void passA_kernel(const float* __restrict__ xyz,
                  const float* __restrict__ features,
                  const int* __restrict__ idx,
                  const float* __restrict__ wl1,
                  const float* __restrict__ wl2,
                  const float* __restrict__ s1a,
                  const float* __restrict__ s1b,
                  const float* __restrict__ bnp,
                  double* __restrict__ dstat) {
  const int br = blockIdx.y;
  const float* W = br ? wl2 : wl1;
  const float* S1 = br ? s1b : s1a;
  __shared__ __align__(16) float encS[4][16 * 40];
  __shared__ __align__(16) float xS[4][16 * 64];
  const int lane = threadIdx.x & 63, wv = threadIdx.x >> 6;
  float* enc = encS[wv];
  float* xL = xS[wv];
  __half2 wh[18];
#pragma unroll
  for (int c = 0; c < 18; ++c)
    wh[c] = __floats2half2_rn(W[lane * 36 + 2 * c], W[lane * 36 + 2 * c + 1]);
  __half2 sh[32];
#pragma unroll
  for (int c = 0; c < 32; ++c)
    sh[c] = __floats2half2_rn(S1[lane * 64 + 2 * c], S1[lane * 64 + 2 * c + 1]);
  const float ym = bnp[DS_Y + br * 64 + lane];
  const float ys = bnp[DS_Y + 128 + br * 64 + lane];
  float zs1 = 0.f, zs2 = 0.f;
  const int wid = blockIdx.x * 4 + wv, nw = gridDim.x * 4;
  GATHER_PROLOGUE
#pragma unroll
    for (int k = 0; k < 16; ++k) {
      float xv = (dot36h(enc + k * 40, wh) - ym) * ys;
      xv = xv > 0.f ? xv : 0.f;
      xL[k * 64 + lane] = xv;
    }
    wavefence();
#pragma unroll
    for (int k = 0; k < 16; ++k) {
      const float acc = dot64h(xL + k * 64, sh);
      zs1 += acc; zs2 += acc * acc;
    }
  GATHER_EPILOGUE
  atomicAdd(&dstat[DS_Z + br * 64 + lane], (double)zs1);
  atomicAdd(&dstat[DS_Z + 128 + br * 64 + lane], (double)zs2);
}

// ---------------- passB: full branch -> g = feat @ mw^T raw; g stats --------
// PLAIN __launch_bounds__(256) -- see passA comment. Round-11 evidence:
// VGPR_Count=64 + FETCH 635MB + WRITE 529MB == entire 567us duration was
// spill bandwidth; round-7's plain bounds had FETCH 31MB at VGPR 136.
__global__ __launch_bounds__(256)
void passB_kernel(const float* __restrict__ xyz,
                  const float* __restrict__ features,
                  const int* __restrict__ idx,
                  const float* __restrict__ wl1,
                  const float* __restrict__ wl2,
                  const float* __restrict__ s1a,
                  const float* __restrict__ s1b,
                  const float* __restrict__ s2a,
                  const float* __restrict__ s2b,
                  const float* __restrict__ sba,
                  const float* __restrict__ sbb,
                  const float* __restrict__ mwa,
                  const float* __restrict__ mwb,
                  const float* __restrict__ bnp,
                  double* __restrict__ dstat,
                  float* __restrict__ graw) {
  const int br = blockIdx.y;
  const float* W = br ? wl2 : wl1;
  const float* S1 = br ? s1b : s1a;
  const float* S2 = br ? s2b : s2a;
  const float* SB = br ? sbb : sba;
  const float* MW = br ? mwb : mwa;
  __shared__ __align__(16) __half2 mwl2[64 * 34];  // row stride 34 pairs (68 halves)
  __shared__ __align__(16) float encS[4][16 * 40];
  __shared__ __align__(16) float xS[4][16 * 64];
  __shared__ __align__(16) float featL[4][64];
  for (int t = threadIdx.x; t < 64 * 32; t += 256) {
    const int r = t >> 5, c2 = t & 31;
    mwl2[r * 34 + c2] = __floats2half2_rn(MW[r * 64 + c2 * 2], MW[r * 64 + c2 * 2 + 1]);
  }
  __syncthreads();  // one-time weight staging only
  const int lane = threadIdx.x & 63, wv = threadIdx.x >> 6;
  float* enc = encS[wv];
  float* xL = xS[wv];
  const __half2* mrow = mwl2 + lane * 34;
  __half2 wh[18];
#pragma unroll
  for (int c = 0; c < 18; ++c)
    wh[c] = __floats2half2_rn(W[lane * 36 + 2 * c], W[lane * 36 + 2 * c + 1]);
  __half2 sh[32];
#pragma unroll
  for (int c = 0; c < 32; ++c)
    sh[c] = __floats2half2_rn(S1[lane * 64 + 2 * c], S1[lane * 64 + 2 * c + 1]);
  const float ym = bnp[DS_Y + br * 64 + lane];
  const float ys = bnp[DS_Y + 128 + br * 64 + lane];
  const float zm = bnp[DS_Z + br * 64 + lane];
  const float zs = bnp[DS_Z + 128 + br * 64 + lane];
  const float sw2r = S2[lane];
  const float sb2v = SB[0];
  float gs1 = 0.f, gs2 = 0.f;
  const int wid = blockIdx.x * 4 + wv, nw = gridDim.x * 4;
  GATHER_PROLOGUE
#pragma unroll
    for (int k = 0; k < 16; ++k) {
      float xv = (dot36h(enc + k * 40, wh) - ym) * ys;
      xv = xv > 0.f ? xv : 0.f;
      xL[k * 64 + lane] = xv;
    }
    wavefence();
    float pl[16];
#pragma unroll
    for (int k = 0; k < 16; ++k) {
      float h = (dot64h(xL + k * 64, sh) - zm) * zs;
      h = h > 0.f ? h : 0.f;
      pl[k] = h * sw2r;
    }
#pragma unroll
    for (int off = 1; off < 64; off <<= 1) {
#pragma unroll
      for (int k = 0; k < 16; ++k) pl[k] += __shfl_xor(pl[k], off, 64);
    }
    float mx = -FLT_MAX;
#pragma unroll
    for (int k = 0; k < 16; ++k) { pl[k] += sb2v; mx = fmaxf(mx, pl[k]); }
    float se = 0.f;
#pragma unroll
    for (int k = 0; k < 16; ++k) { pl[k] = expf(pl[k] - mx); se += pl[k]; }
    const float inv = 1.f / se;
    float f = 0.f;
#pragma unroll
    for (int k = 0; k < 16; ++k) f += xL[k * 64 + lane] * (pl[k] * inv);
    featL[wv][lane] = f;
    wavefence();
    const float* featW = &featL[wv][0];
    float g0 = 0.f, g1 = 0.f, g2 = 0.f, g3 = 0.f;
#pragma unroll
    for (int c8 = 0; c8 < 8; ++c8) {
      const float4 fa = *(const float4*)(featW + c8 * 8);
      const float4 fb = *(const float4*)(featW + c8 * 8 + 4);
      const __half2 m0 = mrow[c8 * 4 + 0];
      const __half2 m1 = mrow[c8 * 4 + 1];
      const __half2 m2 = mrow[c8 * 4 + 2];
      const __half2 m3 = mrow[c8 * 4 + 3];
      g0 += fa.x * __low2float(m0); g1 += fa.y * __high2float(m0);
      g2 += fa.z * __low2float(m1); g3 += fa.w * __high2float(m1);
      g0 += fb.x * __low2float(m2); g1 += fb.y * __high2float(m2);
      g2 += fb.z * __low2float(m3); g3 += fb.w * __high2float(m3);
    }
    const float g = (g0 + g1) + (g2 + g3);
    graw[((size_t)br * PTS + p) * 64 + lane] = g;
    gs1 += g; gs2 += g * g;
  GATHER_EPILOGUE
  atomicAdd(&dstat[DS_G + br * 64 + lane], (double)gs1);
  atomicAdd(&dstat[DS_G + 128 + br * 64 + lane], (double)gs2);
}

// ---------------- DRB matmul stage (128x128 per-point matvec + stats) -------
__global__ __launch_bounds__(256) void drb_mm_kernel(const float* __restrict__ in,
                                                     const float* __restrict__ wmat,
                                                     const float* __restrict__ bnp,
                                                     double* __restrict__ dstat,
                                                     float* __restrict__ aggout,
                                                     float* __restrict__ rowout,
                                                     int bpIn, int dsOut, int mode) {
  __shared__ __align__(16) float wlds[128 * 129];
  __shared__ __align__(16) float rowS[4][128];
  for (int t = threadIdx.x; t < 128 * 128; t += 256) wlds[(t >> 7) * 129 + (t & 127)] = wmat[t];
  __syncthreads();  // one-time weight staging only
  const int lane = threadIdx.x & 63, wv = threadIdx.x >> 6;
  const float m0 = bnp[bpIn + lane], s0 = bnp[bpIn + 128 + lane];
  const float m1 = bnp[bpIn + 64 + lane], s1 = bnp[bpIn + 128 + 64 + lane];
  float a1s0 = 0.f, a1s1 = 0.f, a2s0 = 0.f, a2s1 = 0.f;
  const int wid = blockIdx.x * 4 + wv, nw = gridDim.x * 4;
  for (int p = wid; p < PTS; p += nw) {
    float v0, v1;
    if (mode == 0) {  // input = g_raw [2][PTS][64]
      v0 = in[(size_t)p * 64 + lane];
      v1 = in[(size_t)PTS * 64 + (size_t)p * 64 + lane];
    } else {          // input = h1 raw [PTS][128]
      v0 = in[(size_t)p * 128 + lane];
      v1 = in[(size_t)p * 128 + 64 + lane];
    }
    v0 = (v0 - m0) * s0; v0 = v0 > 0.f ? v0 : 0.f;
    v1 = (v1 - m1) * s1; v1 = v1 > 0.f ? v1 : 0.f;
    rowS[wv][lane] = v0;
    rowS[wv][64 + lane] = v1;
    if (aggout) {
      aggout[(size_t)p * 128 + lane] = v0;
      aggout[(size_t)p * 128 + 64 + lane] = v1;
    }
    wavefence();
#pragma unroll
    for (int h = 0; h < 2; ++h) {
      const int o = h * 64 + lane;
      float b0 = 0.f, b1 = 0.f, b2 = 0.f, b3 = 0.f;
#pragma unroll
      for (int c4 = 0; c4 < 32; ++c4) {
        const float4 rv = *(const float4*)(&rowS[wv][c4 * 4]);
        b0 += rv.x * wlds[o * 129 + c4 * 4 + 0];
        b1 += rv.y * wlds[o * 129 + c4 * 4 + 1];
        b2 += rv.z * wlds[o * 129 + c4 * 4 + 2];
        b3 += rv.w * wlds[o * 129 + c4 * 4 + 3];
      }
      const float acc = (b0 + b1) + (b2 + b3);
      rowout[(size_t)p * 128 + o] = acc;
      if (h == 0) { a1s0 += acc; a2s0 += acc * acc; }
      else        { a1s1 += acc; a2s1 += acc * acc; }
    }
    wavefence();
  }
  atomicAdd(&dstat[dsOut + lane], (double)a1s0);
  atomicAdd(&dstat[dsOut + 64 + lane], (double)a1s1);
  atomicAdd(&dstat[dsOut + 128 + lane], (double)a2s0);
  atomicAdd(&dstat[dsOut + 128 + 64 + lane], (double)a2s1);
}

// ---------------- final: out = relu(bn(h2) + agg) ---------------------------
__global__ __launch_bounds__(256) void final_kernel(const float* __restrict__ h2,
                                                    const float* __restrict__ agg,
                                                    const float* __restrict__ bnp,
                                                    float* __restrict__ out) {
  const size_t e = (size_t)blockIdx.x * 256 + threadIdx.x;
  const int ch = (int)(e & 127);
  const float m = bnp[DS_H2 + ch], s = bnp[DS_H2 + 128 + ch];
  float v = (h2[e] - m) * s + agg[e];
  out[e] = v > 0.f ? v : 0.f;
}

extern "C" void kernel_launch(void* const* d_in, const int* in_sizes, int n_in,
                              void* d_out, int out_size, void* d_ws, size_t ws_size,
                              hipStream_t stream) {
  (void)in_sizes; (void)n_in; (void)out_size; (void)ws_size;
  const float* xyz      = (const float*)d_in[0];
  const float* features = (const float*)d_in[1];
  const float* w_lse1   = (const float*)d_in[2];
  const float* w_lse2   = (const float*)d_in[3];
  const float* ap1_sw1  = (const float*)d_in[4];
  const float* ap1_sw2  = (const float*)d_in[5];
  const float* ap1_sb2  = (const float*)d_in[6];
  const float* ap1_mw   = (const float*)d_in[7];
  const float* ap2_sw1  = (const float*)d_in[8];
  const float* ap2_sw2  = (const float*)d_in[9];
  const float* ap2_sb2  = (const float*)d_in[10];
  const float* ap2_mw   = (const float*)d_in[11];
  const float* drb_w1   = (const float*)d_in[12];
  const float* drb_w2   = (const float*)d_in[13];

  char* ws = (char*)d_ws;
  float*  knn_d = (float*)(ws + OFF_A);
  int*    knn_j = (int*)(ws + OFF_B);
  int*    idx   = (int*)(ws + OFF_IDX);
  double* dstat = (double*)(ws + OFF_DST);
  float*  mstat = (float*)(ws + OFF_MST);
  float*  bnp   = (float*)(ws + OFF_BNP);
  float*  graw  = (float*)(ws + OFF_A);   // reuse after knn done
  float*  agg   = (float*)(ws + OFF_B);   // reuse after knn done
  float*  h1    = (float*)(ws + OFF_H1);
  float*  h2    = (float*)(ws + OFF_H2);
  float*  out   = (float*)d_out;

  // zero dstat (1280 doubles) + mstat (36*37 floats, contiguous after)
  (void)hipMemsetAsync(dstat, 0, 1280 * sizeof(double) + 36 * 37 * sizeof(float), stream);

  knn_chunk_kernel<<<dim3(Nq / 256, CH, Bq), 256, 0, stream>>>(xyz, knn_d, knn_j);
  knn_merge_kernel<<<dim3(PTS / 256), 256, 0, stream>>>(knn_d, knn_j, idx);

  encM_kernel<<<dim3(1280), 256, 0, stream>>>(xyz, features, idx, mstat);
  y_finalize_kernel<<<1, 128, 0, stream>>>(mstat, w_lse1, w_lse2, bnp);

  passA_kernel<<<dim3(512, 2), 256, 0, stream>>>(xyz, features, idx, w_lse1, w_lse2,
                                                 ap1_sw1, ap2_sw1, bnp, dstat);
  bn_finalize_kernel<<<1, 128, 0, stream>>>(dstat, bnp, DS_Z, 1.0 / ROWS);

  passB_kernel<<<dim3(512, 2), 256, 0, stream>>>(xyz, features, idx, w_lse1, w_lse2,
                                                 ap1_sw1, ap2_sw1, ap1_sw2, ap2_sw2,
                                                 ap1_sb2, ap2_sb2, ap1_mw, ap2_mw,
                                                 bnp, dstat, graw);
  bn_finalize_kernel<<<1, 128, 0, stream>>>(dstat, bnp, DS_G, 1.0 / PTS);

  drb_mm_kernel<<<dim3(512), 256, 0, stream>>>(graw, drb_w1, bnp, dstat, agg, h1,
                                               DS_G, DS_H1, 0);
  bn_finalize_kernel<<<1, 128, 0, stream>>>(dstat, bnp, DS_H1, 1.0 / PTS);

  drb_mm_kernel<<<dim3(512), 256, 0, stream>>>(h1, drb_w2, bnp, dstat, nullptr, h2,
                                               DS_H1, DS_H2, 1);
  bn_finalize_kernel<<<1, 128, 0, stream>>>(dstat, bnp, DS_H2, 1.0 / PTS);

  final_kernel<<<dim3(PTS * 128 / 256), 256, 0, stream>>>(h2, agg, bnp, out);
}

// Round 13
// 1654.711 us; speedup vs baseline: 1.0862x; 1.0862x over previous
//
#include <hip/hip_runtime.h>
#include <hip/hip_bf16.h>
#include <hip/hip_fp16.h>
#include <float.h>
#include <math.h>

#define DEVFN __device__ __forceinline__

// Compiler-only fence: wave64 executes DS ops in order; stops reordering.
DEVFN void wavefence() { __builtin_amdgcn_wave_barrier(); }

namespace {
constexpr int Bq = 4, Nq = 8192, Cq = 32, Kq = 16;
constexpr int PTS = Bq * Nq;          // 32768 points
constexpr int CH = 8;                  // knn candidate chunks
constexpr int CAND = Nq / CH;          // 1024 candidates per chunk
constexpr double ROWS = 524288.0;      // PTS * Kq

// dstat/bnp region bases (each region: [sum|mean x128][sumsq|scale x128])
constexpr int DS_Y = 0, DS_Z = 256, DS_G = 512, DS_H1 = 768, DS_H2 = 1024;

// workspace byte offsets
constexpr size_t OFF_A    = 0;                         // knn_d (16MB) -> reused as g_raw
constexpr size_t OFF_B    = (size_t)16 << 20;          // knn_j (16MB) -> reused as agg
constexpr size_t OFF_IDX  = (size_t)32 << 20;          // idx (2MB)
constexpr size_t OFF_DST  = (size_t)34 << 20;          // dstat (1280 doubles)
constexpr size_t OFF_MST  = ((size_t)34 << 20) + 10240; // mstat (36*37 floats)
constexpr size_t OFF_BNP  = ((size_t)34 << 20) + 16384; // bnp (1280 floats)
constexpr size_t OFF_H1   = ((size_t)34 << 20) + 32768; // h1 raw (16MB)
constexpr size_t OFF_H2   = ((size_t)50 << 20) + 32768; // h2 raw (16MB)
}

// ---------------- KNN: two-phase select-then-collect ------------------------
#define TOP16_DECL                                                           \
  float e0=FLT_MAX,e1=FLT_MAX,e2=FLT_MAX,e3=FLT_MAX,e4=FLT_MAX,e5=FLT_MAX,  \
        e6=FLT_MAX,e7=FLT_MAX,e8=FLT_MAX,e9=FLT_MAX,e10=FLT_MAX,            \
        e11=FLT_MAX,e12=FLT_MAX,e13=FLT_MAX,e14=FLT_MAX,e15=FLT_MAX;

// Pair-merge: merge sorted e0..e15 with sorted pair (b0<=b1), keep 16 smallest.
#define PMERGE(i, im1, im2)                                                  \
  e##i = fminf(fminf(e##i, fmaxf(e##im1, b0)), fmaxf(e##im2, b1));
#define PMERGE_ALL                                                           \
  PMERGE(15,14,13) PMERGE(14,13,12) PMERGE(13,12,11) PMERGE(12,11,10)        \
  PMERGE(11,10,9) PMERGE(10,9,8) PMERGE(9,8,7) PMERGE(8,7,6) PMERGE(7,6,5)   \
  PMERGE(6,5,4) PMERGE(5,4,3) PMERGE(4,3,2) PMERGE(3,2,1) PMERGE(2,1,0)      \
  e1 = fminf(fminf(e1, fmaxf(e0, b0)), b1);                                  \
  e0 = fminf(e0, b0);

DEVFN float distf(const float4 c, const float qx, const float qy, const float qz) {
  const float dx = qx - c.x, dy = qy - c.y, dz = qz - c.z;
  return __fadd_rn(__fadd_rn(__fmul_rn(dx, dx), __fmul_rn(dy, dy)), __fmul_rn(dz, dz));
}

__global__ __launch_bounds__(256, 4) void knn_chunk_kernel(const float* __restrict__ xyz,
                                                           float* __restrict__ pd,
                                                           int* __restrict__ pj) {
  const int b = blockIdx.z;
  const int ch = blockIdx.y;
  const int n = blockIdx.x * 256 + threadIdx.x;
  __shared__ __align__(16) float4 tile[CAND];
  const float* xb = xyz + (size_t)b * Nq * 3;
  for (int t = threadIdx.x; t < CAND; t += 256) {
    const int j = ch * CAND + t;
    tile[t] = make_float4(xb[j * 3], xb[j * 3 + 1], xb[j * 3 + 2], 0.f);
  }
  __syncthreads();
  const float qx = xb[n * 3], qy = xb[n * 3 + 1], qz = xb[n * 3 + 2];
  TOP16_DECL;
  for (int t = 0; t < CAND; t += 2) {
    const float u0 = distf(tile[t], qx, qy, qz);
    const float u1 = distf(tile[t + 1], qx, qy, qz);
    const float b0 = fminf(u0, u1), b1 = fmaxf(u0, u1);
    PMERGE_ALL
  }
  const float kth = e15;
  const size_t base = (((size_t)b * Nq + n) * CH + ch) * Kq;
  int cnt = 0, tfirst = -1;
  for (int t = 0; t < CAND; ++t) {
    const float d = distf(tile[t], qx, qy, qz);
    if (d < kth) { pd[base + cnt] = d; pj[base + cnt] = ch * CAND + t; ++cnt; }
    tfirst = (d == kth && tfirst < 0) ? t : tfirst;
  }
  if (cnt == 15) {  // typical (all-distinct): exactly one kth tie -> done
    pd[base + 15] = kth; pj[base + 15] = ch * CAND + tfirst; cnt = 16;
  }
  if (__any(cnt < 16)) {  // rare multi-tie fallback (exactness)
    for (int t = 0; t < CAND; ++t) {
      const float d = distf(tile[t], qx, qy, qz);
      if (d == kth && cnt < 16) { pd[base + cnt] = d; pj[base + cnt] = ch * CAND + t; ++cnt; }
    }
  }
}

__global__ __launch_bounds__(256, 4) void knn_merge_kernel(const float* __restrict__ pd,
                                                           const int* __restrict__ pj,
                                                           int* __restrict__ idxo) {
  const int q = blockIdx.x * 256 + threadIdx.x;
  const float* dp = pd + (size_t)q * CH * Kq;
  const int* jp = pj + (size_t)q * CH * Kq;
  TOP16_DECL;
  for (int t = 0; t < CH * Kq; t += 4) {
    const float4 v = *(const float4*)(dp + t);
    { const float b0 = fminf(v.x, v.y), b1 = fmaxf(v.x, v.y); PMERGE_ALL }
    { const float b0 = fminf(v.z, v.w), b1 = fmaxf(v.z, v.w); PMERGE_ALL }
  }
  const float kth = e15;
  int* op = idxo + (size_t)q * Kq;
  int cnt = 0;
  for (int t = 0; t < CH * Kq; ++t) {
    const float d = dp[t];
    if (d < kth) { op[cnt] = jp[t]; ++cnt; }
  }
  for (int t = 0; t < CH * Kq; ++t) {
    const float d = dp[t];
    if (d == kth && cnt < 16) { op[cnt] = jp[t]; ++cnt; }
  }
}

// ---------------- gather pipeline pieces ------------------------------------
struct PF { float4 f0, f1; float nx, ny, nz; };

DEVFN PF issue_feat(const float* __restrict__ features, const float* __restrict__ xyz,
                    int p, int j, int sub) {
  const int b = p >> 13;
  const float* fr = features + ((size_t)b * Nq + j) * Cq;
  const float* xb = xyz + ((size_t)b * Nq + j) * 3;
  PF r;
  r.f0 = *(const float4*)(fr + sub * 8);
  r.f1 = *(const float4*)(fr + sub * 8 + 4);
  r.nx = xb[0]; r.ny = xb[1]; r.nz = xb[2];
  return r;
}

DEVFN int issue_idx(const int* __restrict__ idx, int p, int lane) {
  return idx[(size_t)p * Kq + (lane >> 2)];
}

DEVFN float3 issue_query(const float* __restrict__ xyz, int p) {
  const float* q = xyz + (size_t)p * 3;  // [B,N,3] flat: p = b*Nq+n
  return make_float3(q[0], q[1], q[2]);
}

// enc row layout (f16, STORED-space): [f0..f31 (32h), rel.x rel.y rel.z dist
// (4h), pad (4h zero)] = 40 halves = 80B/row. Round-12 post-mortem: passA
// matched the LDS model (400 broadcast b128/pt x 12cyc = 512us ~ measured
// 534us) -> LDS data-path bound. f16 rows halve bytes: 208 b128/pt.
DEVFN void commit_enc(__half* __restrict__ enc, int lane, const PF& pf,
                      float qx, float qy, float qz) {
  const int k = lane >> 2, sub = lane & 3;
  __half* er = enc + k * 40;
  union { float4 f; __half2 h[4]; } u;
  u.h[0] = __floats2half2_rn(pf.f0.x, pf.f0.y);
  u.h[1] = __floats2half2_rn(pf.f0.z, pf.f0.w);
  u.h[2] = __floats2half2_rn(pf.f1.x, pf.f1.y);
  u.h[3] = __floats2half2_rn(pf.f1.z, pf.f1.w);
  *(float4*)(er + sub * 8) = u.f;    // byte 80k+16*sub: 16B aligned
  if (sub == 0) {
    const float rx = pf.nx - qx, ry = pf.ny - qy, rz = pf.nz - qz;
    const float ss = rx * rx + ry * ry + rz * rz;
    const float dd = sqrtf(fmaxf(ss, 1e-12f));
    __half2* rd = (__half2*)(er + 32);
    rd[0] = __floats2half2_rn(rx, ry);
    rd[1] = __floats2half2_rn(rz, dd);
  }
}

// zero the 4 pad halves of each of the wave's 16 rows (once per launch;
// pad weights are also zero -- double-safe against NaN garbage).
DEVFN void zero_enc_pad(__half* __restrict__ enc, int lane) {
  if (lane < 16) {
    const __half2 z2 = __floats2half2_rn(0.f, 0.f);
    __half2* pz = (__half2*)(enc + lane * 40 + 36);
    pz[0] = z2; pz[1] = z2;
  }
}

// dot(enc_row (40 f16), wh2[20]) -- 5 b128 reads, 4 accumulators, v_fma_mix.
DEVFN float dot40h(const __half* __restrict__ er, const __half2* __restrict__ wh2) {
  float a0 = 0.f, a1 = 0.f, a2 = 0.f, a3 = 0.f;
#pragma unroll
  for (int r = 0; r < 5; ++r) {
    union { float4 f; __half2 h[4]; } u;
    u.f = *(const float4*)(er + r * 8);
#pragma unroll
    for (int q = 0; q < 4; ++q) {
      const __half2 xv = u.h[q];
      const __half2 wv = wh2[r * 4 + q];
      if (q & 1) {
        a2 += __low2float(xv) * __low2float(wv);
        a3 += __high2float(xv) * __high2float(wv);
      } else {
        a0 += __low2float(xv) * __low2float(wv);
        a1 += __high2float(xv) * __high2float(wv);
      }
    }
  }
  return (a0 + a1) + (a2 + a3);
}

// dot(x_row (64 f16), sh2[32]) -- 8 b128 reads.
DEVFN float dot64x(const __half* __restrict__ xr, const __half2* __restrict__ sh2) {
  float a0 = 0.f, a1 = 0.f, a2 = 0.f, a3 = 0.f;
#pragma unroll
  for (int r = 0; r < 8; ++r) {
    union { float4 f; __half2 h[4]; } u;
    u.f = *(const float4*)(xr + r * 8);
#pragma unroll
    for (int q = 0; q < 4; ++q) {
      const __half2 xv = u.h[q];
      const __half2 wv = sh2[r * 4 + q];
      if (q & 1) {
        a2 += __low2float(xv) * __low2float(wv);
        a3 += __high2float(xv) * __high2float(wv);
      } else {
        a0 += __low2float(xv) * __low2float(wv);
        a1 += __high2float(xv) * __high2float(wv);
      }
    }
  }
  return (a0 + a1) + (a2 + a3);
}

// load lane's 36 weights (original order) into STORED-space f16 pairs:
// pairs 0..15 = features (orig 4..35), 16 = (orig0,orig1), 17 = (orig2,orig3),
// 18,19 = zero (pads).
DEVFN void load_w40(const float* __restrict__ Wrow, __half2* wh2) {
#pragma unroll
  for (int c = 0; c < 16; ++c)
    wh2[c] = __floats2half2_rn(Wrow[4 + 2 * c], Wrow[5 + 2 * c]);
  wh2[16] = __floats2half2_rn(Wrow[0], Wrow[1]);
  wh2[17] = __floats2half2_rn(Wrow[2], Wrow[3]);
  wh2[18] = __floats2half2_rn(0.f, 0.f);
  wh2[19] = wh2[18];
}

// pipeline open/close macros (body sits between them as ordinary code).
#define GATHER_PROLOGUE                                                      \
  int p = wid;                                                               \
  int jc = issue_idx(idx, p, lane);                                          \
  PF cur = issue_feat(features, xyz, p, jc, lane & 3);                       \
  float3 qc = issue_query(xyz, p);                                           \
  int pn0 = p + nw; if (pn0 >= PTS) pn0 = p;                                 \
  int jn = issue_idx(idx, pn0, lane);                                        \
  float3 qn = issue_query(xyz, pn0);                                         \
  for (; p < PTS; p += nw) {                                                 \
    int pn = p + nw; if (pn >= PTS) pn = p;                                  \
    int pn2 = pn + nw; if (pn2 >= PTS) pn2 = pn;                             \
    PF nxt = issue_feat(features, xyz, pn, jn, lane & 3);                    \
    const int jn2 = issue_idx(idx, pn2, lane);                               \
    const float3 q2 = issue_query(xyz, pn2);                                 \
    commit_enc(enc, lane, cur, qc.x, qc.y, qc.z);                            \
    wavefence();

#define GATHER_EPILOGUE                                                      \
    wavefence();                                                             \
    cur = nxt; qc = qn; qn = q2; jn = jn2;                                   \
  }

// ---------------- encM: M = sum enc^T enc (36x36 STORED-space), v = sum enc -
__global__ __launch_bounds__(256) void encM_kernel(const float* __restrict__ xyz,
                                                   const float* __restrict__ features,
                                                   const int* __restrict__ idx,
                                                   float* __restrict__ mstat) {
  __shared__ __align__(16) __half encS[4][16 * 40];
  __shared__ float mred[4][36 * 37];
  const int lane = threadIdx.x & 63, wv = threadIdx.x >> 6;
  __half* enc = encS[wv];
  zero_enc_pad(enc, lane);
  wavefence();
  const int li = (lane < 36) ? lane : 0;  // clamp: lanes>=36 compute junk, never stored
  float macc[36];
#pragma unroll
  for (int i = 0; i < 36; ++i) macc[i] = 0.f;
  float vacc = 0.f;
  const int wid = blockIdx.x * 4 + wv, nw = gridDim.x * 4;
  GATHER_PROLOGUE
#pragma unroll
    for (int k = 0; k < 16; ++k) {
      const __half* er = enc + k * 40;
      const float ei = __half2float(er[li]);
      vacc += ei;
#pragma unroll
      for (int r = 0; r < 5; ++r) {
        union { float4 f; __half2 h[4]; } u;
        u.f = *(const float4*)(er + r * 8);
#pragma unroll
        for (int q = 0; q < 4; ++q) {
          const int s = r * 8 + 2 * q;
          if (s < 36)     macc[s]     += ei * __low2float(u.h[q]);
          if (s + 1 < 36) macc[s + 1] += ei * __high2float(u.h[q]);
        }
      }
    }
  GATHER_EPILOGUE
  if (lane < 36) {
#pragma unroll
    for (int j = 0; j < 36; ++j) mred[wv][lane * 37 + j] = macc[j];
    mred[wv][lane * 37 + 36] = vacc;
  }
  __syncthreads();
  for (int t = threadIdx.x; t < 36 * 37; t += 256) {
    const float s = mred[0][t] + mred[1][t] + mred[2][t] + mred[3][t];
    atomicAdd(&mstat[t], s);
  }
}

// y-stat finalize from STORED-space moments. stored s -> original enc index:
// s<32 ? s+4 : s-32 (features first, then rel/dist).
__global__ void y_finalize_kernel(const float* __restrict__ mstat,
                                  const float* __restrict__ wl1,
                                  const float* __restrict__ wl2,
                                  float* __restrict__ bnp) {
  const int t = threadIdx.x;  // 128
  const int br = t >> 6, o = t & 63;
  const float* W = br ? wl2 : wl1;
  double wrow[36];
  for (int s = 0; s < 36; ++s) {
    const int orig = (s < 32) ? (s + 4) : (s - 32);
    wrow[s] = (double)W[o * 36 + orig];
  }
  double mean = 0.0, ey2 = 0.0;
  for (int i = 0; i < 36; ++i) {
    mean += wrow[i] * (double)mstat[i * 37 + 36];
    double rowacc = 0.0;
    for (int j = 0; j < 36; ++j) rowacc += wrow[j] * (double)mstat[i * 37 + j];
    ey2 += wrow[i] * rowacc;
  }
  const double invR = 1.0 / ROWS;
  mean *= invR; ey2 *= invR;
  const double var = ey2 - mean * mean;
  bnp[DS_Y + br * 64 + o] = (float)mean;
  bnp[DS_Y + 128 + br * 64 + o] = (float)(1.0 / sqrt(var + 1e-5));
}

// ---------------- generic BN stat finalize: mean + rsqrt(var+eps) -----------
__global__ void bn_finalize_kernel(const double* __restrict__ dstat, float* __restrict__ bnp,
                                   int base, double invc) {
  const int t = threadIdx.x;  // 128 threads
  const double m = dstat[base + t] * invc;
  const double v = dstat[base + 128 + t] * invc - m * m;
  bnp[base + t] = (float)m;
  bnp[base + 128 + t] = (float)(1.0 / sqrt(v + 1e-5));
}

// ---------------- passA: x = relu(bn(y)); z = x @ sw1^T; z stats ------------
// PLAIN __launch_bounds__(256) (occupancy hints cause 64-VGPR spill, r8-r11).
// enc+x in f16 LDS: 208 b128/pt vs 400 -> LDS-path floor ~266us.
__global__ __launch_bounds__(256)
void passA_kernel(const float* __restrict__ xyz,
                  const float* __restrict__ features,
                  const int* __restrict__ idx,
                  const float* __restrict__ wl1,
                  const float* __restrict__ wl2,
                  const float* __restrict__ s1a,
                  const float* __restrict__ s1b,
                  const float* __restrict__ bnp,
                  double* __restrict__ dstat) {
  const int br = blockIdx.y;
  const float* W = br ? wl2 : wl1;
  const float* S1 = br ? s1b : s1a;
  __shared__ __align__(16) __half encS[4][16 * 40];
  __shared__ __align__(16) __half xS[4][16 * 64];
  const int lane = threadIdx.x & 63, wv = threadIdx.x >> 6;
  __half* enc = encS[wv];
  __half* xL = xS[wv];
  zero_enc_pad(enc, lane);
  wavefence();
  __half2 wh2[20];
  load_w40(W + lane * 36, wh2);
  __half2 sh2[32];
#pragma unroll
  for (int c = 0; c < 32; ++c)
    sh2[c] = __floats2half2_rn(S1[lane * 64 + 2 * c], S1[lane * 64 + 2 * c + 1]);
  const float ym = bnp[DS_Y + br * 64 + lane];
  const float ys = bnp[DS_Y + 128 + br * 64 + lane];
  float zs1 = 0.f, zs2 = 0.f;
  const int wid = blockIdx.x * 4 + wv, nw = gridDim.x * 4;
  GATHER_PROLOGUE
#pragma unroll
    for (int k = 0; k < 16; ++k) {
      float xv = (dot40h(enc + k * 40, wh2) - ym) * ys;
      xv = xv > 0.f ? xv : 0.f;
      xL[k * 64 + lane] = __float2half(xv);
    }
    wavefence();
#pragma unroll
    for (int k = 0; k < 16; ++k) {
      const float acc = dot64x(xL + k * 64, sh2);
      zs1 += acc; zs2 += acc * acc;
    }
  GATHER_EPILOGUE
  atomicAdd(&dstat[DS_Z + br * 64 + lane], (double)zs1);
  atomicAdd(&dstat[DS_Z + 128 + br * 64 + lane], (double)zs2);
}

// ---------------- passB: full branch -> g = feat @ mw^T raw; g stats --------
__global__ __launch_bounds__(256)
void passB_kernel(const float* __restrict__ xyz,
                  const float* __restrict__ features,
                  const int* __restrict__ idx,
                  const float* __restrict__ wl1,
                  const float* __restrict__ wl2,
                  const float* __restrict__ s1a,
                  const float* __restrict__ s1b,
                  const float* __restrict__ s2a,
                  const float* __restrict__ s2b,
                  const float* __restrict__ sba,
                  const float* __restrict__ sbb,
                  const float* __restrict__ mwa,
                  const float* __restrict__ mwb,
                  const float* __restrict__ bnp,
                  double* __restrict__ dstat,
                  float* __restrict__ graw) {
  const int br = blockIdx.y;
  const float* W = br ? wl2 : wl1;
  const float* S1 = br ? s1b : s1a;
  const float* S2 = br ? s2b : s2a;
  const float* SB = br ? sbb : sba;
  const float* MW = br ? mwb : mwa;
  __shared__ __align__(16) __half2 mwl2[64 * 34];  // row stride 34 pairs (68 halves)
  __shared__ __align__(16) __half encS[4][16 * 40];
  __shared__ __align__(16) __half xS[4][16 * 64];
  __shared__ __align__(16) float featL[4][64];
  for (int t = threadIdx.x; t < 64 * 32; t += 256) {
    const int r = t >> 5, c2 = t & 31;
    mwl2[r * 34 + c2] = __floats2half2_rn(MW[r * 64 + c2 * 2], MW[r * 64 + c2 * 2 + 1]);
  }
  __syncthreads();  // one-time weight staging only
  const int lane = threadIdx.x & 63, wv = threadIdx.x >> 6;
  __half* enc = encS[wv];
  __half* xL = xS[wv];
  zero_enc_pad(enc, lane);
  wavefence();
  const __half2* mrow = mwl2 + lane * 34;
  __half2 wh2[20];
  load_w40(W + lane * 36, wh2);
  __half2 sh2[32];
#pragma unroll
  for (int c = 0; c < 32; ++c)
    sh2[c] = __floats2half2_rn(S1[lane * 64 + 2 * c], S1[lane * 64 + 2 * c + 1]);
  const float ym = bnp[DS_Y + br * 64 + lane];
  const float ys = bnp[DS_Y + 128 + br * 64 + lane];
  const float zm = bnp[DS_Z + br * 64 + lane];
  const float zs = bnp[DS_Z + 128 + br * 64 + lane];
  const float sw2r = S2[lane];
  const float sb2v = SB[0];
  float gs1 = 0.f, gs2 = 0.f;
  const int wid = blockIdx.x * 4 + wv, nw = gridDim.x * 4;
  GATHER_PROLOGUE
#pragma unroll
    for (int k = 0; k < 16; ++k) {
      float xv = (dot40h(enc + k * 40, wh2) - ym) * ys;
      xv = xv > 0.f ? xv : 0.f;
      xL[k * 64 + lane] = __float2half(xv);
    }
    wavefence();
    float pl[16];
#pragma unroll
    for (int k = 0; k < 16; ++k) {
      float h = (dot64x(xL + k * 64, sh2) - zm) * zs;
      h = h > 0.f ? h : 0.f;
      pl[k] = h * sw2r;
    }
#pragma unroll
    for (int off = 1; off < 64; off <<= 1) {
#pragma unroll
      for (int k = 0; k < 16; ++k) pl[k] += __shfl_xor(pl[k], off, 64);
    }
    float mx = -FLT_MAX;
#pragma unroll
    for (int k = 0; k < 16; ++k) { pl[k] += sb2v; mx = fmaxf(mx, pl[k]); }
    float se = 0.f;
#pragma unroll
    for (int k = 0; k < 16; ++k) { pl[k] = expf(pl[k] - mx); se += pl[k]; }
    const float inv = 1.f / se;
    float f = 0.f;
#pragma unroll
    for (int k = 0; k < 16; ++k) f += __half2float(xL[k * 64 + lane]) * (pl[k] * inv);
    featL[wv][lane] = f;
    wavefence();
    const float* featW = &featL[wv][0];
    float g0 = 0.f, g1 = 0.f, g2 = 0.f, g3 = 0.f;
#pragma unroll
    for (int c8 = 0; c8 < 8; ++c8) {
      const float4 fa = *(const float4*)(featW + c8 * 8);
      const float4 fb = *(const float4*)(featW + c8 * 8 + 4);
      const __half2 m0 = mrow[c8 * 4 + 0];
      const __half2 m1 = mrow[c8 * 4 + 1];
      const __half2 m2 = mrow[c8 * 4 + 2];
      const __half2 m3 = mrow[c8 * 4 + 3];
      g0 += fa.x * __low2float(m0); g1 += fa.y * __high2float(m0);
      g2 += fa.z * __low2float(m1); g3 += fa.w * __high2float(m1);
      g0 += fb.x * __low2float(m2); g1 += fb.y * __high2float(m2);
      g2 += fb.z * __low2float(m3); g3 += fb.w * __high2float(m3);
    }
    const float g = (g0 + g1) + (g2 + g3);
    graw[((size_t)br * PTS + p) * 64 + lane] = g;
    gs1 += g; gs2 += g * g;
  GATHER_EPILOGUE
  atomicAdd(&dstat[DS_G + br * 64 + lane], (double)gs1);
  atomicAdd(&dstat[DS_G + 128 + br * 64 + lane], (double)gs2);
}

// ---------------- DRB matmul stage (128x128 per-point matvec + stats) -------
__global__ __launch_bounds__(256) void drb_mm_kernel(const float* __restrict__ in,
                                                     const float* __restrict__ wmat,
                                                     const float* __restrict__ bnp,
                                                     double* __restrict__ dstat,
                                                     float* __restrict__ aggout,
                                                     float* __restrict__ rowout,
                                                     int bpIn, int dsOut, int mode) {
  __shared__ __align__(16) float wlds[128 * 129];
  __shared__ __align__(16) float rowS[4][128];
  for (int t = threadIdx.x; t < 128 * 128; t += 256) wlds[(t >> 7) * 129 + (t & 127)] = wmat[t];
  __syncthreads();  // one-time weight staging only
  const int lane = threadIdx.x & 63, wv = threadIdx.x >> 6;
  const float m0 = bnp[bpIn + lane], s0 = bnp[bpIn + 128 + lane];
  const float m1 = bnp[bpIn + 64 + lane], s1 = bnp[bpIn + 128 + 64 + lane];
  float a1s0 = 0.f, a1s1 = 0.f, a2s0 = 0.f, a2s1 = 0.f;
  const int wid = blockIdx.x * 4 + wv, nw = gridDim.x * 4;
  for (int p = wid; p < PTS; p += nw) {
    float v0, v1;
    if (mode == 0) {  // input = g_raw [2][PTS][64]
      v0 = in[(size_t)p * 64 + lane];
      v1 = in[(size_t)PTS * 64 + (size_t)p * 64 + lane];
    } else {          // input = h1 raw [PTS][128]
      v0 = in[(size_t)p * 128 + lane];
      v1 = in[(size_t)p * 128 + 64 + lane];
    }
    v0 = (v0 - m0) * s0; v0 = v0 > 0.f ? v0 : 0.f;
    v1 = (v1 - m1) * s1; v1 = v1 > 0.f ? v1 : 0.f;
    rowS[wv][lane] = v0;
    rowS[wv][64 + lane] = v1;
    if (aggout) {
      aggout[(size_t)p * 128 + lane] = v0;
      aggout[(size_t)p * 128 + 64 + lane] = v1;
    }
    wavefence();
#pragma unroll
    for (int h = 0; h < 2; ++h) {
      const int o = h * 64 + lane;
      float b0 = 0.f, b1 = 0.f, b2 = 0.f, b3 = 0.f;
#pragma unroll
      for (int c4 = 0; c4 < 32; ++c4) {
        const float4 rv = *(const float4*)(&rowS[wv][c4 * 4]);
        b0 += rv.x * wlds[o * 129 + c4 * 4 + 0];
        b1 += rv.y * wlds[o * 129 + c4 * 4 + 1];
        b2 += rv.z * wlds[o * 129 + c4 * 4 + 2];
        b3 += rv.w * wlds[o * 129 + c4 * 4 + 3];
      }
      const float acc = (b0 + b1) + (b2 + b3);
      rowout[(size_t)p * 128 + o] = acc;
      if (h == 0) { a1s0 += acc; a2s0 += acc * acc; }
      else        { a1s1 += acc; a2s1 += acc * acc; }
    }
    wavefence();
  }
  atomicAdd(&dstat[dsOut + lane], (double)a1s0);
  atomicAdd(&dstat[dsOut + 64 + lane], (double)a1s1);
  atomicAdd(&dstat[dsOut + 128 + lane], (double)a2s0);
  atomicAdd(&dstat[dsOut + 128 + 64 + lane], (double)a2s1);
}

// ---------------- final: out = relu(bn(h2) + agg) ---------------------------
__global__ __launch_bounds__(256) void final_kernel(const float* __restrict__ h2,
                                                    const float* __restrict__ agg,
                                                    const float* __restrict__ bnp,
                                                    float* __restrict__ out) {
  const size_t e = (size_t)blockIdx.x * 256 + threadIdx.x;
  const int ch = (int)(e & 127);
  const float m = bnp[DS_H2 + ch], s = bnp[DS_H2 + 128 + ch];
  float v = (h2[e] - m) * s + agg[e];
  out[e] = v > 0.f ? v : 0.f;
}

extern "C" void kernel_launch(void* const* d_in, const int* in_sizes, int n_in,
                              void* d_out, int out_size, void* d_ws, size_t ws_size,
                              hipStream_t stream) {
  (void)in_sizes; (void)n_in; (void)out_size; (void)ws_size;
  const float* xyz      = (const float*)d_in[0];
  const float* features = (const float*)d_in[1];
  const float* w_lse1   = (const float*)d_in[2];
  const float* w_lse2   = (const float*)d_in[3];
  const float* ap1_sw1  = (const float*)d_in[4];
  const float* ap1_sw2  = (const float*)d_in[5];
  const float* ap1_sb2  = (const float*)d_in[6];
  const float* ap1_mw   = (const float*)d_in[7];
  const float* ap2_sw1  = (const float*)d_in[8];
  const float* ap2_sw2  = (const float*)d_in[9];
  const float* ap2_sb2  = (const float*)d_in[10];
  const float* ap2_mw   = (const float*)d_in[11];
  const float* drb_w1   = (const float*)d_in[12];
  const float* drb_w2   = (const float*)d_in[13];

  char* ws = (char*)d_ws;
  float*  knn_d = (float*)(ws + OFF_A);
  int*    knn_j = (int*)(ws + OFF_B);
  int*    idx   = (int*)(ws + OFF_IDX);
  double* dstat = (double*)(ws + OFF_DST);
  float*  mstat = (float*)(ws + OFF_MST);
  float*  bnp   = (float*)(ws + OFF_BNP);
  float*  graw  = (float*)(ws + OFF_A);   // reuse after knn done
  float*  agg   = (float*)(ws + OFF_B);   // reuse after knn done
  float*  h1    = (float*)(ws + OFF_H1);
  float*  h2    = (float*)(ws + OFF_H2);
  float*  out   = (float*)d_out;

  // zero dstat (1280 doubles) + mstat (36*37 floats, contiguous after)
  (void)hipMemsetAsync(dstat, 0, 1280 * sizeof(double) + 36 * 37 * sizeof(float), stream);

  knn_chunk_kernel<<<dim3(Nq / 256, CH, Bq), 256, 0, stream>>>(xyz, knn_d, knn_j);
  knn_merge_kernel<<<dim3(PTS / 256), 256, 0, stream>>>(knn_d, knn_j, idx);

  encM_kernel<<<dim3(1280), 256, 0, stream>>>(xyz, features, idx, mstat);
  y_finalize_kernel<<<1, 128, 0, stream>>>(mstat, w_lse1, w_lse2, bnp);

  passA_kernel<<<dim3(640, 2), 256, 0, stream>>>(xyz, features, idx, w_lse1, w_lse2,
                                                 ap1_sw1, ap2_sw1, bnp, dstat);
  bn_finalize_kernel<<<1, 128, 0, stream>>>(dstat, bnp, DS_Z, 1.0 / ROWS);

  passB_kernel<<<dim3(512, 2), 256, 0, stream>>>(xyz, features, idx, w_lse1, w_lse2,
                                                 ap1_sw1, ap2_sw1, ap1_sw2, ap2_sw2,
                                                 ap1_sb2, ap2_sb2, ap1_mw, ap2_mw,
                                                 bnp, dstat, graw);
  bn_finalize_kernel<<<1, 128, 0, stream>>>(dstat, bnp, DS_G, 1.0 / PTS);

  drb_mm_kernel<<<dim3(512), 256, 0, stream>>>(graw, drb_w1, bnp, dstat, agg, h1,
                                               DS_G, DS_H1, 0);
  bn_finalize_kernel<<<1, 128, 0, stream>>>(dstat, bnp, DS_H1, 1.0 / PTS);

  drb_mm_kernel<<<dim3(512), 256, 0, stream>>>(h1, drb_w2, bnp, dstat, nullptr, h2,
                                               DS_H1, DS_H2, 1);
  bn_finalize_kernel<<<1, 128, 0, stream>>>(dstat, bnp, DS_H2, 1.0 / PTS);

  final_kernel<<<dim3(PTS * 128 / 256), 256, 0, stream>>>(h2, agg, bnp, out);
}